// Round 5
// baseline (1808.122 us; speedup 1.0000x reference)
//
#include <hip/hip_runtime.h>
#include <hip/hip_bf16.h>
#include <cstdint>
#include <math.h>

using bf16 = __hip_bfloat16;
typedef __attribute__((ext_vector_type(4))) float f32x4;
typedef __attribute__((ext_vector_type(8))) short s16x8;
typedef __attribute__((ext_vector_type(4))) short s16x4;

#define AS3(p) ((__attribute__((address_space(3))) void *)(p))
#define AS1(p) ((const __attribute__((address_space(1))) void *)(p))

static constexpr int Himg = 256, Wimg = 256, Bimg = 4;
static constexpr int HWimg = Himg * Wimg;
static constexpr int Ttok = Bimg * HWimg;   // 262144 tokens

__device__ __forceinline__ void gld16(bf16* lds, const bf16* g) {
  __builtin_amdgcn_global_load_lds(AS1(g), AS3(lds), 16, 0, 0);
}

__device__ __forceinline__ unsigned short f2u(float f) {
  bf16 b = __float2bfloat16(f);
  unsigned short u; __builtin_memcpy(&u, &b, 2); return u;
}

// XCD-chunked remap: hw round-robin (bid%8) -> contiguous logical chunks.
__device__ __forceinline__ void remap_tile(int bid, int total, int NY, int& t0, int& n0) {
  int lin = (bid & 7) * (total >> 3) + (bid >> 3);
  t0 = (lin / NY) * 128;
  n0 = (lin % NY) * 128;
}

// ---------------- prep kernels ----------------
__global__ void k_zero4k(float* p) {
  p[blockIdx.x * 256 + threadIdx.x] = 0.f;
}

__global__ void k_castf2b(const float* __restrict__ s, bf16* __restrict__ d, int n) {
  int i = blockIdx.x * 256 + threadIdx.x;
  if (i < n) d[i] = __float2bfloat16(s[i]);
}

__global__ void k_copyf(const float* __restrict__ s, float* __restrict__ d, int n) {
  int i = blockIdx.x * 256 + threadIdx.x;
  if (i < n) d[i] = s[i];
}

// conv weight permute: OIHW fp32 -> [O][tap][I] bf16
__global__ void k_permconv(const float* __restrict__ w, bf16* __restrict__ o, int I) {
  int idx = blockIdx.x * 256 + threadIdx.x;
  int tot = 256 * 9 * I;
  if (idx >= tot) return;
  int i   = idx % I;
  int rem = idx / I;
  int tap = rem % 9;
  int oc  = rem / 9;
  o[idx] = __float2bfloat16(w[(oc * I + i) * 9 + tap]);
}

// NCHW fp32 -> NHWC bf16
__global__ void k_tohwc(const float* __restrict__ src, bf16* __restrict__ dst, int C) {
  int bh = blockIdx.x;
  int w0 = blockIdx.y * 32;
  int c0 = blockIdx.z * 32;
  int b = bh / Himg, h = bh % Himg;
  __shared__ float tile[32][33];
  int tid = threadIdx.x;
  int x = tid & 31, y = tid >> 5;
  const float* sp = src + (size_t)b * C * HWimg + (size_t)h * Wimg;
#pragma unroll
  for (int p = 0; p < 4; ++p) {
    int cl = y + p * 8;
    tile[cl][x] = sp[(size_t)(c0 + cl) * HWimg + w0 + x];
  }
  __syncthreads();
#pragma unroll
  for (int p = 0; p < 4; ++p) {
    int wl = y + p * 8;
    dst[((size_t)bh * Wimg + w0 + wl) * C + c0 + x] = __float2bfloat16(tile[x][wl]);
  }
}

// NHWC fp32 -> NCHW fp32 (final output)
__global__ void k_tochw(const float* __restrict__ src, float* __restrict__ dst) {
  int bh = blockIdx.x, w0 = blockIdx.y * 32, c0 = blockIdx.z * 32;
  int b = bh >> 8, h = bh & 255;
  __shared__ float tile[32][33];
  int tid = threadIdx.x, x = tid & 31, y = tid >> 5;
  const float* sp = src + (size_t)bh * Wimg * 256;
#pragma unroll
  for (int p = 0; p < 4; ++p) {
    int wl = y + p * 8;
    tile[wl][x] = sp[(size_t)(w0 + wl) * 256 + c0 + x];
  }
  __syncthreads();
#pragma unroll
  for (int p = 0; p < 4; ++p) {
    int cl = y + p * 8;
    dst[(((size_t)b * 256 + c0 + cl) * Himg + h) * Wimg + w0 + x] = tile[x][cl];
  }
}

// ---------------- implicit-GEMM / conv kernel (triple-buffer, counted vmcnt) ----------------
// EPI 0: outb[t*ldo+col] = bf16(acc+bias)
// EPI 2: outf[t*256+col] = acc + bias + float(ident[t*256+col])   (NHWC fp32)
template <int CIN, int TAPS, int EPI>
__global__ void __launch_bounds__(256, 3)
k_gemm(const bf16* __restrict__ Ain, const bf16* __restrict__ BT,
       const float* __restrict__ bias,
       bf16* __restrict__ outb, int ldo,
       float* __restrict__ outf, const bf16* __restrict__ ident,
       const bf16* __restrict__ zp, int NY)
{
  constexpr int KTOT = TAPS * CIN;
  constexpr int NK = KTOT / 32;
  int t0, n0;
  remap_tile(blockIdx.x, gridDim.x, NY, t0, n0);
  const int tid = threadIdx.x;
  const int wave = tid >> 6, lane = tid & 63;
  const int seg = lane & 3;
  const int rr  = lane >> 2;

  __shared__ bf16 sA[3][128 * 32];
  __shared__ bf16 sB[3][128 * 32];

  f32x4 acc[4][4] = {};

  const int wr = wave >> 1, wc = wave & 1;
  const int fr = lane & 15, fq = lane >> 4;

  auto stage = [&](int buf, int ks) {
    const int k0 = ks * 32;
    const int tap = k0 / CIN;
    const int c0  = k0 - tap * CIN;
    const int dy  = tap / 3 - 1, dx = tap % 3 - 1;
#pragma unroll
    for (int i = 0; i < 2; ++i) {
      const int r = wave * 32 + i * 16 + rr;
      const int t = t0 + r;
      const bf16* src;
      if (TAPS == 1) {
        src = Ain + (size_t)t * CIN + k0 + seg * 8;
      } else {
        const int h = (t >> 8) & 255, w = t & 255;
        const int hh = h + dy, ww = w + dx;
        const bool valid = ((unsigned)hh < 256u) && ((unsigned)ww < 256u);
        const long gi = (long)t + dy * Wimg + dx;
        src = valid ? (Ain + gi * CIN + c0 + seg * 8) : (zp + seg * 8);
      }
      gld16(sA[buf] + (wave * 32 + i * 16) * 32, src);
      gld16(sB[buf] + (wave * 32 + i * 16) * 32,
            BT + (size_t)(n0 + wave * 32 + i * 16 + rr) * KTOT + k0 + seg * 8);
    }
  };

  stage(0, 0);
  stage(1, 1);
  int bi = 0;
  for (int ks = 0; ks < NK; ++ks) {
    if (ks + 1 < NK) { asm volatile("s_waitcnt vmcnt(4)" ::: "memory"); }
    else             { asm volatile("s_waitcnt vmcnt(0)" ::: "memory"); }
    __builtin_amdgcn_s_barrier();
    asm volatile("" ::: "memory");
    if (ks + 2 < NK) {
      int b2 = bi + 2; if (b2 >= 3) b2 -= 3;
      stage(b2, ks + 2);
    }
    const bf16* pA = sA[bi];
    const bf16* pB = sB[bi];
    s16x8 af[4], bfrag[4];
#pragma unroll
    for (int m = 0; m < 4; ++m)
      af[m] = *(const s16x8*)(pA + (wr * 64 + m * 16 + fr) * 32 + fq * 8);
#pragma unroll
    for (int n = 0; n < 4; ++n)
      bfrag[n] = *(const s16x8*)(pB + (wc * 64 + n * 16 + fr) * 32 + fq * 8);
#pragma unroll
    for (int m = 0; m < 4; ++m)
#pragma unroll
      for (int n = 0; n < 4; ++n)
        acc[m][n] = __builtin_amdgcn_mfma_f32_16x16x32_bf16(af[m], bfrag[n], acc[m][n], 0, 0, 0);
    bi = (bi == 2) ? 0 : bi + 1;
  }

#pragma unroll
  for (int m = 0; m < 4; ++m) {
#pragma unroll
    for (int n = 0; n < 4; ++n) {
      const int col = n0 + wc * 64 + n * 16 + fr;
#pragma unroll
      for (int j = 0; j < 4; ++j) {
        const int row = wr * 64 + m * 16 + fq * 4 + j;
        const size_t t = (size_t)t0 + row;
        float v = acc[m][n][j] + bias[col];
        if (EPI == 0) {
          outb[t * ldo + col] = __float2bfloat16(v);
        } else {
          v += __bfloat162float(ident[t * 256 + col]);
          outf[t * 256 + col] = v;
        }
      }
    }
  }
}

// ---------------- gated dual GEMM (triple-buffer, counted vmcnt) ----------------
// out[t*768+col] = (A_m B_m + b_m) * sigmoid(A_f B_f + b_f), 16-stage flat pipeline.
__global__ void __launch_bounds__(256, 2)
k_gemm_qkv(const bf16* __restrict__ Am, const bf16* __restrict__ Af,
           const bf16* __restrict__ Bm, const bf16* __restrict__ Bf,
           const float* __restrict__ bm, const float* __restrict__ bfi,
           bf16* __restrict__ out)
{
  int t0, n0;
  remap_tile(blockIdx.x, gridDim.x, 4, t0, n0);
  const int tid = threadIdx.x;
  const int wave = tid >> 6, lane = tid & 63;
  const int seg = lane & 3;
  const int rr  = lane >> 2;

  __shared__ bf16 sA[3][128 * 32];
  __shared__ bf16 sB[3][128 * 32];

  f32x4 accm[4][4] = {};
  f32x4 accf[4][4] = {};

  const int wr = wave >> 1, wc = wave & 1;
  const int fr = lane & 15, fq = lane >> 4;

  auto stage = [&](int buf, int s) {
    const int k0 = (s >> 1) * 32;
    const bool useF = (s & 1);
    const bf16* A = useF ? Af : Am;
    const bf16* B = useF ? Bf : Bm;
#pragma unroll
    for (int i = 0; i < 2; ++i) {
      const int r = wave * 32 + i * 16 + rr;
      gld16(sA[buf] + (wave * 32 + i * 16) * 32, A + (size_t)(t0 + r) * 256 + k0 + seg * 8);
      gld16(sB[buf] + (wave * 32 + i * 16) * 32, B + (size_t)(n0 + r) * 256 + k0 + seg * 8);
    }
  };

  stage(0, 0);
  stage(1, 1);
  int bi = 0;
  for (int s = 0; s < 16; ++s) {
    if (s + 1 < 16) { asm volatile("s_waitcnt vmcnt(4)" ::: "memory"); }
    else            { asm volatile("s_waitcnt vmcnt(0)" ::: "memory"); }
    __builtin_amdgcn_s_barrier();
    asm volatile("" ::: "memory");
    if (s + 2 < 16) {
      int b2 = bi + 2; if (b2 >= 3) b2 -= 3;
      stage(b2, s + 2);
    }
    const bf16* pA = sA[bi];
    const bf16* pB = sB[bi];
    s16x8 af[4], bfrag[4];
#pragma unroll
    for (int m = 0; m < 4; ++m)
      af[m] = *(const s16x8*)(pA + (wr * 64 + m * 16 + fr) * 32 + fq * 8);
#pragma unroll
    for (int n = 0; n < 4; ++n)
      bfrag[n] = *(const s16x8*)(pB + (wc * 64 + n * 16 + fr) * 32 + fq * 8);
    if (s & 1) {
#pragma unroll
      for (int m = 0; m < 4; ++m)
#pragma unroll
        for (int n = 0; n < 4; ++n)
          accf[m][n] = __builtin_amdgcn_mfma_f32_16x16x32_bf16(af[m], bfrag[n], accf[m][n], 0, 0, 0);
    } else {
#pragma unroll
      for (int m = 0; m < 4; ++m)
#pragma unroll
        for (int n = 0; n < 4; ++n)
          accm[m][n] = __builtin_amdgcn_mfma_f32_16x16x32_bf16(af[m], bfrag[n], accm[m][n], 0, 0, 0);
    }
    bi = (bi == 2) ? 0 : bi + 1;
  }

#pragma unroll
  for (int m = 0; m < 4; ++m) {
#pragma unroll
    for (int n = 0; n < 4; ++n) {
      const int col = n0 + wc * 64 + n * 16 + fr;
#pragma unroll
      for (int j = 0; j < 4; ++j) {
        const int row = wr * 64 + m * 16 + fq * 4 + j;
        const size_t t = (size_t)t0 + row;
        float v = accm[m][n][j] + bm[col];
        const float g = accf[m][n][j] + bfi[col];
        v *= 1.f / (1.f + __expf(-g));
        out[t * 768 + col] = __float2bfloat16(v);
      }
    }
  }
}

// ---------------- MFMA window attention (coalesced LDS staging) ----------------
__global__ void __launch_bounds__(256, 2)
k_attn_mfma(const bf16* __restrict__ qkv, bf16* __restrict__ out) {
  __shared__ short smem[4 * 7424];   // 14848 B per wave
  const int tid = threadIdx.x;
  const int wave = tid >> 6, lane = tid & 63;
  const int fr = lane & 15, fq = lane >> 4;
  const int wi = blockIdx.x >> 1;
  const int head = (blockIdx.x & 1) * 4 + wave;
  const int b = wi >> 10, rem = wi & 1023, wh = rem >> 5, ww = rem & 31;
  const size_t tbase = (size_t)b * HWimg + (size_t)(wh * 8) * Wimg + ww * 8;

  short* Qs = smem + wave * 7424;     // [64][40]
  short* Ks = Qs + 2560;              // [64][40]
  short* VT = Qs + 5120;              // [32][72]
  short* P  = Qs;                     // [64][72] alias
  short* Ol = Qs;                     // [64][40] alias

  auto tok = [&](int i) -> size_t {
    return tbase + (size_t)(i >> 3) * Wimg + (i & 7);
  };

  {
    const bf16* tb = qkv + tok(lane) * 768 + head * 32;
#pragma unroll
    for (int c = 0; c < 4; ++c) {
      s16x8 qv = *(const s16x8*)(tb + c * 8);
      s16x8 kv = *(const s16x8*)(tb + 256 + c * 8);
      s16x8 vv = *(const s16x8*)(tb + 512 + c * 8);
      *(s16x8*)(Qs + lane * 40 + c * 8) = qv;
      *(s16x8*)(Ks + lane * 40 + c * 8) = kv;
#pragma unroll
      for (int e = 0; e < 8; ++e) VT[(c * 8 + e) * 72 + lane] = vv[e];
    }
  }

  s16x8 kf[4], qf[4];
#pragma unroll
  for (int m = 0; m < 4; ++m)
    kf[m] = *(const s16x8*)(Ks + (fr + 16 * m) * 40 + fq * 8);
#pragma unroll
  for (int n = 0; n < 4; ++n)
    qf[n] = *(const s16x8*)(Qs + (fr + 16 * n) * 40 + fq * 8);

  f32x4 st[4][4] = {};
#pragma unroll
  for (int m = 0; m < 4; ++m)
#pragma unroll
    for (int n = 0; n < 4; ++n)
      st[m][n] = __builtin_amdgcn_mfma_f32_16x16x32_bf16(kf[m], qf[n], st[m][n], 0, 0, 0);

  const float scale = 0.17677669529663688f;  // 1/sqrt(32)
  float invs[4];
#pragma unroll
  for (int n = 0; n < 4; ++n) {
    float mx = -1e30f;
#pragma unroll
    for (int m = 0; m < 4; ++m)
#pragma unroll
      for (int j = 0; j < 4; ++j) mx = fmaxf(mx, st[m][n][j]);
    mx = fmaxf(mx, __shfl_xor(mx, 16));
    mx = fmaxf(mx, __shfl_xor(mx, 32));
    float sum = 0.f;
#pragma unroll
    for (int m = 0; m < 4; ++m) {
      s16x4 pk;
#pragma unroll
      for (int j = 0; j < 4; ++j) {
        float e = __expf((st[m][n][j] - mx) * scale);
        sum += e;
        pk[j] = (short)f2u(e);
      }
      *(s16x4*)(P + (fr + 16 * n) * 72 + 16 * m + 4 * fq) = pk;
    }
    sum += __shfl_xor(sum, 16);
    sum += __shfl_xor(sum, 32);
    invs[n] = 1.f / sum;
  }

  f32x4 oc[4][2] = {};
#pragma unroll
  for (int ks = 0; ks < 2; ++ks) {
    s16x8 pf[4], vf[2];
#pragma unroll
    for (int m = 0; m < 4; ++m)
      pf[m] = *(const s16x8*)(P + (fr + 16 * m) * 72 + ks * 32 + fq * 8);
#pragma unroll
    for (int n = 0; n < 2; ++n)
      vf[n] = *(const s16x8*)(VT + (fr + 16 * n) * 72 + ks * 32 + fq * 8);
#pragma unroll
    for (int m = 0; m < 4; ++m)
#pragma unroll
      for (int n = 0; n < 2; ++n)
        oc[m][n] = __builtin_amdgcn_mfma_f32_16x16x32_bf16(pf[m], vf[n], oc[m][n], 0, 0, 0);
  }

#pragma unroll
  for (int m = 0; m < 4; ++m)
#pragma unroll
    for (int j = 0; j < 4; ++j) {
      const float inv = __shfl(invs[m], 4 * fq + j);
      const int q = 16 * m + 4 * fq + j;
#pragma unroll
      for (int n = 0; n < 2; ++n)
        Ol[q * 40 + fr + 16 * n] = (short)f2u(oc[m][n][j] * inv);
    }
  {
    bf16* op = out + tok(lane) * 256 + head * 32;
#pragma unroll
    for (int c = 0; c < 4; ++c)
      *(s16x8*)(op + c * 8) = *(const s16x8*)(Ol + lane * 40 + c * 8);
  }
}

// ---------------- host ----------------
extern "C" void kernel_launch(void* const* d_in, const int* in_sizes, int n_in,
                              void* d_out, int out_size, void* d_ws, size_t ws_size,
                              hipStream_t stream) {
  const float* xmap    = (const float*)d_in[0];
  const float* xfeat   = (const float*)d_in[1];
  const float* cmap_w  = (const float*)d_in[2];
  const float* cmap_b  = (const float*)d_in[3];
  const float* cfeat_w = (const float*)d_in[4];
  const float* cfeat_b = (const float*)d_in[5];
  const float* qxmap_w = (const float*)d_in[6];
  const float* qxmap_b = (const float*)d_in[7];
  const float* kxmap_w = (const float*)d_in[8];
  const float* kxmap_b = (const float*)d_in[9];
  const float* vxmap_w = (const float*)d_in[10];
  const float* vxmap_b = (const float*)d_in[11];
  const float* qxfeat_w = (const float*)d_in[12];
  const float* qxfeat_b = (const float*)d_in[13];
  const float* kxfeat_w = (const float*)d_in[14];
  const float* kxfeat_b = (const float*)d_in[15];
  const float* proj_w  = (const float*)d_in[16];
  const float* proj_b  = (const float*)d_in[17];
  const float* cout_w  = (const float*)d_in[18];
  const float* cout_b  = (const float*)d_in[19];

  uint8_t* ws = (uint8_t*)d_ws;
  size_t off = 0;
  auto alloc = [&](size_t bytes) -> void* {
    void* p = ws + off;
    off += (bytes + 255) & ~(size_t)255;
    return p;
  };
  float* zp       = (float*)alloc(4096);
  bf16* cmap_wT   = (bf16*)alloc((size_t)2304 * 256 * 2);
  bf16* cout_wT   = (bf16*)alloc((size_t)2304 * 256 * 2);
  bf16* cfeat_wT  = (bf16*)alloc((size_t)288 * 256 * 2);
  bf16* lin_qkv_wT= (bf16*)alloc((size_t)768 * 256 * 2);
  bf16* lin_f_wT  = (bf16*)alloc((size_t)512 * 256 * 2);
  bf16* proj_wT   = (bf16*)alloc((size_t)256 * 256 * 2);
  float* bias_qkv = (float*)alloc(768 * 4);
  float* bias_f   = (float*)alloc(512 * 4);
  bf16* xm_nhwc   = (bf16*)alloc((size_t)Ttok * 256 * 2);
  bf16* xf_nhwc   = (bf16*)alloc((size_t)Ttok * 32 * 2);
  bf16* xc        = (bf16*)alloc((size_t)Ttok * 256 * 2);
  bf16* fc        = (bf16*)alloc((size_t)Ttok * 256 * 2);
  bf16* qkv       = (bf16*)alloc((size_t)Ttok * 768 * 2);
  bf16* attn_out  = xm_nhwc;          // reuse (dead after cmap conv)
  bf16* proj_out  = fc;               // reuse (dead after qkv GEMMs)
  float* convout  = (float*)qkv;      // reuse (dead after attention)
  bf16* zpb = (bf16*)zp;

  k_zero4k<<<4, 256, 0, stream>>>(zp);
  k_permconv<<<(256 * 9 * 256 + 255) / 256, 256, 0, stream>>>(cmap_w, cmap_wT, 256);
  k_permconv<<<(256 * 9 * 256 + 255) / 256, 256, 0, stream>>>(cout_w, cout_wT, 256);
  k_permconv<<<(256 * 9 * 32 + 255) / 256, 256, 0, stream>>>(cfeat_w, cfeat_wT, 32);
  k_castf2b<<<256, 256, 0, stream>>>(qxmap_w, lin_qkv_wT, 65536);
  k_castf2b<<<256, 256, 0, stream>>>(kxmap_w, lin_qkv_wT + 65536, 65536);
  k_castf2b<<<256, 256, 0, stream>>>(vxmap_w, lin_qkv_wT + 131072, 65536);
  k_castf2b<<<256, 256, 0, stream>>>(qxfeat_w, lin_f_wT, 65536);
  k_castf2b<<<256, 256, 0, stream>>>(kxfeat_w, lin_f_wT + 65536, 65536);
  k_castf2b<<<256, 256, 0, stream>>>(proj_w, proj_wT, 65536);
  k_copyf<<<1, 256, 0, stream>>>(qxmap_b, bias_qkv, 256);
  k_copyf<<<1, 256, 0, stream>>>(kxmap_b, bias_qkv + 256, 256);
  k_copyf<<<1, 256, 0, stream>>>(vxmap_b, bias_qkv + 512, 256);
  k_copyf<<<1, 256, 0, stream>>>(qxfeat_b, bias_f, 256);
  k_copyf<<<1, 256, 0, stream>>>(kxfeat_b, bias_f + 256, 256);

  k_tohwc<<<dim3(Bimg * Himg, Wimg / 32, 256 / 32), 256, 0, stream>>>(xmap, xm_nhwc, 256);
  k_tohwc<<<dim3(Bimg * Himg, Wimg / 32, 1), 256, 0, stream>>>(xfeat, xf_nhwc, 32);

  dim3 blk(256);
  const int NT = Ttok / 128;   // 2048 row tiles
  // conv cmap -> xc
  k_gemm<256, 9, 0><<<dim3(NT * 2), blk, 0, stream>>>(
      xm_nhwc, cmap_wT, cmap_b, xc, 256, nullptr, nullptr, zpb, 2);
  // conv cfeat -> fc
  k_gemm<32, 9, 0><<<dim3(NT * 2), blk, 0, stream>>>(
      xf_nhwc, cfeat_wT, cfeat_b, fc, 256, nullptr, nullptr, zpb, 2);
  // v-linear -> qkv[:,512:768]
  k_gemm<256, 1, 0><<<dim3(NT * 2), blk, 0, stream>>>(
      xc, lin_qkv_wT + 131072, bias_qkv + 512, qkv + 512, 768, nullptr, nullptr, zpb, 2);
  // gated q,k -> qkv[:,0:512]
  k_gemm_qkv<<<dim3(NT * 4), blk, 0, stream>>>(
      xc, fc, lin_qkv_wT, lin_f_wT, bias_qkv, bias_f, qkv);
  // MFMA window attention
  k_attn_mfma<<<dim3(4096 * 2), blk, 0, stream>>>(qkv, attn_out);
  // proj GEMM
  k_gemm<256, 1, 0><<<dim3(NT * 2), blk, 0, stream>>>(
      attn_out, proj_wT, proj_b, proj_out, 256, nullptr, nullptr, zpb, 2);
  // conv cout + bias + identity -> convout (NHWC fp32)
  k_gemm<256, 9, 2><<<dim3(NT * 2), blk, 0, stream>>>(
      proj_out, cout_wT, cout_b, nullptr, 0, convout, xc, zpb, 2);
  // NHWC -> NCHW final
  k_tochw<<<dim3(Bimg * Himg, Wimg / 32, 256 / 32), 256, 0, stream>>>(convout, (float*)d_out);
}

// Round 6
// 1652.933 us; speedup vs baseline: 1.0939x; 1.0939x over previous
//
#include <hip/hip_runtime.h>
#include <hip/hip_bf16.h>
#include <cstdint>
#include <math.h>

using bf16 = __hip_bfloat16;
typedef __attribute__((ext_vector_type(4))) float f32x4;
typedef __attribute__((ext_vector_type(8))) short s16x8;
typedef __attribute__((ext_vector_type(4))) short s16x4;

#define AS3(p) ((__attribute__((address_space(3))) void *)(p))
#define AS1(p) ((const __attribute__((address_space(1))) void *)(p))

static constexpr int Himg = 256, Wimg = 256, Bimg = 4;
static constexpr int HWimg = Himg * Wimg;
static constexpr int Ttok = Bimg * HWimg;   // 262144 tokens

__device__ __forceinline__ void gld16(bf16* lds, const bf16* g) {
  __builtin_amdgcn_global_load_lds(AS1(g), AS3(lds), 16, 0, 0);
}

__device__ __forceinline__ unsigned short f2u(float f) {
  bf16 b = __float2bfloat16(f);
  unsigned short u; __builtin_memcpy(&u, &b, 2); return u;
}

// XCD-chunked remap: hw round-robin (bid%8) -> contiguous logical chunks.
__device__ __forceinline__ void remap_tile(int bid, int total, int NY, int& t0, int& n0) {
  int lin = (bid & 7) * (total >> 3) + (bid >> 3);
  t0 = (lin / NY) * 128;
  n0 = (lin % NY) * 128;
}

// ---------------- prep kernels ----------------
__global__ void k_zero4k(float* p) {
  p[blockIdx.x * 256 + threadIdx.x] = 0.f;
}

__global__ void k_castf2b(const float* __restrict__ s, bf16* __restrict__ d, int n) {
  int i = blockIdx.x * 256 + threadIdx.x;
  if (i < n) d[i] = __float2bfloat16(s[i]);
}

__global__ void k_copyf(const float* __restrict__ s, float* __restrict__ d, int n) {
  int i = blockIdx.x * 256 + threadIdx.x;
  if (i < n) d[i] = s[i];
}

// conv weight permute: OIHW fp32 -> [O][tap][I] bf16
__global__ void k_permconv(const float* __restrict__ w, bf16* __restrict__ o, int I) {
  int idx = blockIdx.x * 256 + threadIdx.x;
  int tot = 256 * 9 * I;
  if (idx >= tot) return;
  int i   = idx % I;
  int rem = idx / I;
  int tap = rem % 9;
  int oc  = rem / 9;
  o[idx] = __float2bfloat16(w[(oc * I + i) * 9 + tap]);
}

// NCHW fp32 -> NHWC bf16
__global__ void k_tohwc(const float* __restrict__ src, bf16* __restrict__ dst, int C) {
  int bh = blockIdx.x;
  int w0 = blockIdx.y * 32;
  int c0 = blockIdx.z * 32;
  int b = bh / Himg, h = bh % Himg;
  __shared__ float tile[32][33];
  int tid = threadIdx.x;
  int x = tid & 31, y = tid >> 5;
  const float* sp = src + (size_t)b * C * HWimg + (size_t)h * Wimg;
#pragma unroll
  for (int p = 0; p < 4; ++p) {
    int cl = y + p * 8;
    tile[cl][x] = sp[(size_t)(c0 + cl) * HWimg + w0 + x];
  }
  __syncthreads();
#pragma unroll
  for (int p = 0; p < 4; ++p) {
    int wl = y + p * 8;
    dst[((size_t)bh * Wimg + w0 + wl) * C + c0 + x] = __float2bfloat16(tile[x][wl]);
  }
}

// NHWC bf16 -> NCHW fp32 (final output)
__global__ void k_tochw(const bf16* __restrict__ src, float* __restrict__ dst) {
  int bh = blockIdx.x, w0 = blockIdx.y * 32, c0 = blockIdx.z * 32;
  int b = bh >> 8, h = bh & 255;
  __shared__ float tile[32][33];
  int tid = threadIdx.x, x = tid & 31, y = tid >> 5;
  const bf16* sp = src + (size_t)bh * Wimg * 256;
#pragma unroll
  for (int p = 0; p < 4; ++p) {
    int wl = y + p * 8;
    tile[wl][x] = __bfloat162float(sp[(size_t)(w0 + wl) * 256 + c0 + x]);
  }
  __syncthreads();
#pragma unroll
  for (int p = 0; p < 4; ++p) {
    int cl = y + p * 8;
    dst[(((size_t)b * 256 + c0 + cl) * Himg + h) * Wimg + w0 + x] = tile[x][cl];
  }
}

// ---------------- implicit-GEMM / conv kernel ----------------
// Triple-buffered, STATICALLY-NAMED LDS buffers + counted vmcnt pipeline.
// EPI 0: outb[t*ldo+col] = bf16(acc+bias)
// EPI 2: outb[t*256+col] = bf16(acc + bias + float(ident[t*256+col]))
template <int CIN, int TAPS, int EPI>
__global__ void __launch_bounds__(256, 3)
k_gemm(const bf16* __restrict__ Ain, const bf16* __restrict__ BT,
       const float* __restrict__ bias,
       bf16* __restrict__ outb, int ldo,
       const bf16* __restrict__ ident,
       const bf16* __restrict__ zp, int NY)
{
  constexpr int KTOT = TAPS * CIN;
  constexpr int NK = KTOT / 32;
  int t0, n0;
  remap_tile(blockIdx.x, gridDim.x, NY, t0, n0);
  const int tid = threadIdx.x;
  const int wave = tid >> 6, lane = tid & 63;
  const int seg = lane & 3;
  const int rr  = lane >> 2;

  __shared__ bf16 sA0[128 * 32];
  __shared__ bf16 sA1[128 * 32];
  __shared__ bf16 sA2[128 * 32];
  __shared__ bf16 sB0[128 * 32];
  __shared__ bf16 sB1[128 * 32];
  __shared__ bf16 sB2[128 * 32];

  f32x4 acc[4][4] = {};

  const int wr = wave >> 1, wc = wave & 1;
  const int fr = lane & 15, fq = lane >> 4;

#define STAGE(WA, WB, KSV) do {                                                 \
    const int k0_ = (KSV) * 32;                                                 \
    const int tap_ = k0_ / CIN;                                                 \
    const int c0_ = k0_ - tap_ * CIN;                                           \
    const int dy_ = tap_ / 3 - 1, dx_ = tap_ % 3 - 1;                           \
    _Pragma("unroll") for (int i_ = 0; i_ < 2; ++i_) {                          \
      const int r_ = wave * 32 + i_ * 16 + rr;                                  \
      const int t_ = t0 + r_;                                                   \
      const bf16* src_;                                                         \
      if (TAPS == 1) {                                                          \
        src_ = Ain + (size_t)t_ * CIN + k0_ + seg * 8;                          \
      } else {                                                                  \
        const int hh_ = ((t_ >> 8) & 255) + dy_, ww_ = (t_ & 255) + dx_;        \
        const bool v_ = ((unsigned)hh_ < 256u) && ((unsigned)ww_ < 256u);       \
        const long gi_ = (long)t_ + dy_ * Wimg + dx_;                           \
        src_ = v_ ? (Ain + gi_ * CIN + c0_ + seg * 8) : (zp + seg * 8);         \
      }                                                                         \
      gld16(WA + (wave * 32 + i_ * 16) * 32, src_);                             \
      gld16(WB + (wave * 32 + i_ * 16) * 32,                                    \
            BT + (size_t)(n0 + wave * 32 + i_ * 16 + rr) * KTOT + k0_ + seg * 8); \
    }                                                                           \
  } while (0)

#define GSTEP(RA, RB, WA, WB, KSV, LASTF) do {                                  \
    if (LASTF) { asm volatile("s_waitcnt vmcnt(0)" ::: "memory"); }             \
    else       { asm volatile("s_waitcnt vmcnt(4)" ::: "memory"); }             \
    __builtin_amdgcn_s_barrier();                                               \
    s16x8 af_[4], bf_[4];                                                       \
    _Pragma("unroll") for (int m_ = 0; m_ < 4; ++m_)                            \
      af_[m_] = *(const s16x8*)(RA + (wr * 64 + m_ * 16 + fr) * 32 + fq * 8);   \
    _Pragma("unroll") for (int n_ = 0; n_ < 4; ++n_)                            \
      bf_[n_] = *(const s16x8*)(RB + (wc * 64 + n_ * 16 + fr) * 32 + fq * 8);   \
    if ((KSV) + 2 < NK) STAGE(WA, WB, (KSV) + 2);                               \
    __builtin_amdgcn_s_setprio(1);                                              \
    _Pragma("unroll") for (int m_ = 0; m_ < 4; ++m_)                            \
      _Pragma("unroll") for (int n_ = 0; n_ < 4; ++n_)                          \
        acc[m_][n_] = __builtin_amdgcn_mfma_f32_16x16x32_bf16(af_[m_], bf_[n_], acc[m_][n_], 0, 0, 0); \
    __builtin_amdgcn_s_setprio(0);                                              \
  } while (0)

  STAGE(sA0, sB0, 0);
  STAGE(sA1, sB1, 1);

  constexpr int NMAIN = ((NK - 1) / 3) * 3;   // main-loop steps, multiple of 3, < NK
  int ks = 0;
#pragma unroll 1
  for (; ks < NMAIN; ks += 3) {
    GSTEP(sA0, sB0, sA2, sB2, ks,     false);
    GSTEP(sA1, sB1, sA0, sB0, ks + 1, false);
    GSTEP(sA2, sB2, sA1, sB1, ks + 2, false);
  }
  constexpr int TREM = NK - NMAIN;            // 1..3 tail steps
  if constexpr (TREM == 3) {
    GSTEP(sA0, sB0, sA2, sB2, NMAIN,     false);
    GSTEP(sA1, sB1, sA0, sB0, NMAIN + 1, false);
    GSTEP(sA2, sB2, sA1, sB1, NMAIN + 2, true);
  } else if constexpr (TREM == 2) {
    GSTEP(sA0, sB0, sA2, sB2, NMAIN,     false);
    GSTEP(sA1, sB1, sA0, sB0, NMAIN + 1, true);
  } else {
    GSTEP(sA0, sB0, sA2, sB2, NMAIN,     true);
  }
#undef GSTEP
#undef STAGE

#pragma unroll
  for (int m = 0; m < 4; ++m) {
#pragma unroll
    for (int n = 0; n < 4; ++n) {
      const int col = n0 + wc * 64 + n * 16 + fr;
#pragma unroll
      for (int j = 0; j < 4; ++j) {
        const int row = wr * 64 + m * 16 + fq * 4 + j;
        const size_t t = (size_t)t0 + row;
        float v = acc[m][n][j] + bias[col];
        if (EPI == 0) {
          outb[t * ldo + col] = __float2bfloat16(v);
        } else {
          v += __bfloat162float(ident[t * 256 + col]);
          outb[t * 256 + col] = __float2bfloat16(v);
        }
      }
    }
  }
}

// ---------------- gated dual GEMM (static triple-buffer pipeline) ----------------
// out[t*768+col] = (A_m B_m + b_m) * sigmoid(A_f B_f + b_f); 16 flat steps (m/f alternating).
__global__ void __launch_bounds__(256, 2)
k_gemm_qkv(const bf16* __restrict__ Am, const bf16* __restrict__ Af,
           const bf16* __restrict__ Bm, const bf16* __restrict__ Bf,
           const float* __restrict__ bm, const float* __restrict__ bfi,
           bf16* __restrict__ out)
{
  int t0, n0;
  remap_tile(blockIdx.x, gridDim.x, 4, t0, n0);
  const int tid = threadIdx.x;
  const int wave = tid >> 6, lane = tid & 63;
  const int seg = lane & 3;
  const int rr  = lane >> 2;

  __shared__ bf16 sA0[128 * 32];
  __shared__ bf16 sA1[128 * 32];
  __shared__ bf16 sA2[128 * 32];
  __shared__ bf16 sB0[128 * 32];
  __shared__ bf16 sB1[128 * 32];
  __shared__ bf16 sB2[128 * 32];

  f32x4 accm[4][4] = {};
  f32x4 accf[4][4] = {};

  const int wr = wave >> 1, wc = wave & 1;
  const int fr = lane & 15, fq = lane >> 4;

#define STAGEQ(WA, WB, SV) do {                                                 \
    const int k0_ = ((SV) >> 1) * 32;                                           \
    const bf16* A_ = ((SV) & 1) ? Af : Am;                                      \
    const bf16* B_ = ((SV) & 1) ? Bf : Bm;                                      \
    _Pragma("unroll") for (int i_ = 0; i_ < 2; ++i_) {                          \
      const int r_ = wave * 32 + i_ * 16 + rr;                                  \
      gld16(WA + (wave * 32 + i_ * 16) * 32, A_ + (size_t)(t0 + r_) * 256 + k0_ + seg * 8); \
      gld16(WB + (wave * 32 + i_ * 16) * 32, B_ + (size_t)(n0 + r_) * 256 + k0_ + seg * 8); \
    }                                                                           \
  } while (0)

#define QSTEP(RA, RB, WA, WB, SV, LASTF) do {                                   \
    if (LASTF) { asm volatile("s_waitcnt vmcnt(0)" ::: "memory"); }             \
    else       { asm volatile("s_waitcnt vmcnt(4)" ::: "memory"); }             \
    __builtin_amdgcn_s_barrier();                                               \
    s16x8 af_[4], bf_[4];                                                       \
    _Pragma("unroll") for (int m_ = 0; m_ < 4; ++m_)                            \
      af_[m_] = *(const s16x8*)(RA + (wr * 64 + m_ * 16 + fr) * 32 + fq * 8);   \
    _Pragma("unroll") for (int n_ = 0; n_ < 4; ++n_)                            \
      bf_[n_] = *(const s16x8*)(RB + (wc * 64 + n_ * 16 + fr) * 32 + fq * 8);   \
    if ((SV) + 2 < 16) STAGEQ(WA, WB, (SV) + 2);                                \
    __builtin_amdgcn_s_setprio(1);                                              \
    if ((SV) & 1) {                                                             \
      _Pragma("unroll") for (int m_ = 0; m_ < 4; ++m_)                          \
        _Pragma("unroll") for (int n_ = 0; n_ < 4; ++n_)                        \
          accf[m_][n_] = __builtin_amdgcn_mfma_f32_16x16x32_bf16(af_[m_], bf_[n_], accf[m_][n_], 0, 0, 0); \
    } else {                                                                    \
      _Pragma("unroll") for (int m_ = 0; m_ < 4; ++m_)                          \
        _Pragma("unroll") for (int n_ = 0; n_ < 4; ++n_)                        \
          accm[m_][n_] = __builtin_amdgcn_mfma_f32_16x16x32_bf16(af_[m_], bf_[n_], accm[m_][n_], 0, 0, 0); \
    }                                                                           \
    __builtin_amdgcn_s_setprio(0);                                              \
  } while (0)

  STAGEQ(sA0, sB0, 0);
  STAGEQ(sA1, sB1, 1);

  int s = 0;
#pragma unroll 1
  for (; s < 15; s += 3) {
    QSTEP(sA0, sB0, sA2, sB2, s,     false);
    QSTEP(sA1, sB1, sA0, sB0, s + 1, false);
    QSTEP(sA2, sB2, sA1, sB1, s + 2, false);
  }
  QSTEP(sA0, sB0, sA2, sB2, 15, true);
#undef QSTEP
#undef STAGEQ

#pragma unroll
  for (int m = 0; m < 4; ++m) {
#pragma unroll
    for (int n = 0; n < 4; ++n) {
      const int col = n0 + wc * 64 + n * 16 + fr;
#pragma unroll
      for (int j = 0; j < 4; ++j) {
        const int row = wr * 64 + m * 16 + fq * 4 + j;
        const size_t t = (size_t)t0 + row;
        float v = accm[m][n][j] + bm[col];
        const float g = accf[m][n][j] + bfi[col];
        v *= 1.f / (1.f + __expf(-g));
        out[t * 768 + col] = __float2bfloat16(v);
      }
    }
  }
}

// ---------------- MFMA window attention (coalesced LDS staging) ----------------
__global__ void __launch_bounds__(256, 2)
k_attn_mfma(const bf16* __restrict__ qkv, bf16* __restrict__ out) {
  __shared__ short smem[4 * 7424];   // 14848 B per wave
  const int tid = threadIdx.x;
  const int wave = tid >> 6, lane = tid & 63;
  const int fr = lane & 15, fq = lane >> 4;
  const int wi = blockIdx.x >> 1;
  const int head = (blockIdx.x & 1) * 4 + wave;
  const int b = wi >> 10, rem = wi & 1023, wh = rem >> 5, ww = rem & 31;
  const size_t tbase = (size_t)b * HWimg + (size_t)(wh * 8) * Wimg + ww * 8;

  short* Qs = smem + wave * 7424;     // [64][40]
  short* Ks = Qs + 2560;              // [64][40]
  short* VT = Qs + 5120;              // [32][72]
  short* P  = Qs;                     // [64][72] alias
  short* Ol = Qs;                     // [64][40] alias

  auto tok = [&](int i) -> size_t {
    return tbase + (size_t)(i >> 3) * Wimg + (i & 7);
  };

  {
    const bf16* tb = qkv + tok(lane) * 768 + head * 32;
#pragma unroll
    for (int c = 0; c < 4; ++c) {
      s16x8 qv = *(const s16x8*)(tb + c * 8);
      s16x8 kv = *(const s16x8*)(tb + 256 + c * 8);
      s16x8 vv = *(const s16x8*)(tb + 512 + c * 8);
      *(s16x8*)(Qs + lane * 40 + c * 8) = qv;
      *(s16x8*)(Ks + lane * 40 + c * 8) = kv;
#pragma unroll
      for (int e = 0; e < 8; ++e) VT[(c * 8 + e) * 72 + lane] = vv[e];
    }
  }

  s16x8 kf[4], qf[4];
#pragma unroll
  for (int m = 0; m < 4; ++m)
    kf[m] = *(const s16x8*)(Ks + (fr + 16 * m) * 40 + fq * 8);
#pragma unroll
  for (int n = 0; n < 4; ++n)
    qf[n] = *(const s16x8*)(Qs + (fr + 16 * n) * 40 + fq * 8);

  f32x4 st[4][4] = {};
#pragma unroll
  for (int m = 0; m < 4; ++m)
#pragma unroll
    for (int n = 0; n < 4; ++n)
      st[m][n] = __builtin_amdgcn_mfma_f32_16x16x32_bf16(kf[m], qf[n], st[m][n], 0, 0, 0);

  const float scale = 0.17677669529663688f;  // 1/sqrt(32)
  float invs[4];
#pragma unroll
  for (int n = 0; n < 4; ++n) {
    float mx = -1e30f;
#pragma unroll
    for (int m = 0; m < 4; ++m)
#pragma unroll
      for (int j = 0; j < 4; ++j) mx = fmaxf(mx, st[m][n][j]);
    mx = fmaxf(mx, __shfl_xor(mx, 16));
    mx = fmaxf(mx, __shfl_xor(mx, 32));
    float sum = 0.f;
#pragma unroll
    for (int m = 0; m < 4; ++m) {
      s16x4 pk;
#pragma unroll
      for (int j = 0; j < 4; ++j) {
        float e = __expf((st[m][n][j] - mx) * scale);
        sum += e;
        pk[j] = (short)f2u(e);
      }
      *(s16x4*)(P + (fr + 16 * n) * 72 + 16 * m + 4 * fq) = pk;
    }
    sum += __shfl_xor(sum, 16);
    sum += __shfl_xor(sum, 32);
    invs[n] = 1.f / sum;
  }

  f32x4 oc[4][2] = {};
#pragma unroll
  for (int ks = 0; ks < 2; ++ks) {
    s16x8 pf[4], vf[2];
#pragma unroll
    for (int m = 0; m < 4; ++m)
      pf[m] = *(const s16x8*)(P + (fr + 16 * m) * 72 + ks * 32 + fq * 8);
#pragma unroll
    for (int n = 0; n < 2; ++n)
      vf[n] = *(const s16x8*)(VT + (fr + 16 * n) * 72 + ks * 32 + fq * 8);
#pragma unroll
    for (int m = 0; m < 4; ++m)
#pragma unroll
      for (int n = 0; n < 2; ++n)
        oc[m][n] = __builtin_amdgcn_mfma_f32_16x16x32_bf16(pf[m], vf[n], oc[m][n], 0, 0, 0);
  }

#pragma unroll
  for (int m = 0; m < 4; ++m)
#pragma unroll
    for (int j = 0; j < 4; ++j) {
      const float inv = __shfl(invs[m], 4 * fq + j);
      const int q = 16 * m + 4 * fq + j;
#pragma unroll
      for (int n = 0; n < 2; ++n)
        Ol[q * 40 + fr + 16 * n] = (short)f2u(oc[m][n][j] * inv);
    }
  {
    bf16* op = out + tok(lane) * 256 + head * 32;
#pragma unroll
    for (int c = 0; c < 4; ++c)
      *(s16x8*)(op + c * 8) = *(const s16x8*)(Ol + lane * 40 + c * 8);
  }
}

// ---------------- host ----------------
extern "C" void kernel_launch(void* const* d_in, const int* in_sizes, int n_in,
                              void* d_out, int out_size, void* d_ws, size_t ws_size,
                              hipStream_t stream) {
  const float* xmap    = (const float*)d_in[0];
  const float* xfeat   = (const float*)d_in[1];
  const float* cmap_w  = (const float*)d_in[2];
  const float* cmap_b  = (const float*)d_in[3];
  const float* cfeat_w = (const float*)d_in[4];
  const float* cfeat_b = (const float*)d_in[5];
  const float* qxmap_w = (const float*)d_in[6];
  const float* qxmap_b = (const float*)d_in[7];
  const float* kxmap_w = (const float*)d_in[8];
  const float* kxmap_b = (const float*)d_in[9];
  const float* vxmap_w = (const float*)d_in[10];
  const float* vxmap_b = (const float*)d_in[11];
  const float* qxfeat_w = (const float*)d_in[12];
  const float* qxfeat_b = (const float*)d_in[13];
  const float* kxfeat_w = (const float*)d_in[14];
  const float* kxfeat_b = (const float*)d_in[15];
  const float* proj_w  = (const float*)d_in[16];
  const float* proj_b  = (const float*)d_in[17];
  const float* cout_w  = (const float*)d_in[18];
  const float* cout_b  = (const float*)d_in[19];

  uint8_t* ws = (uint8_t*)d_ws;
  size_t off = 0;
  auto alloc = [&](size_t bytes) -> void* {
    void* p = ws + off;
    off += (bytes + 255) & ~(size_t)255;
    return p;
  };
  float* zp       = (float*)alloc(4096);
  bf16* cmap_wT   = (bf16*)alloc((size_t)2304 * 256 * 2);
  bf16* cout_wT   = (bf16*)alloc((size_t)2304 * 256 * 2);
  bf16* cfeat_wT  = (bf16*)alloc((size_t)288 * 256 * 2);
  bf16* lin_qkv_wT= (bf16*)alloc((size_t)768 * 256 * 2);
  bf16* lin_f_wT  = (bf16*)alloc((size_t)512 * 256 * 2);
  bf16* proj_wT   = (bf16*)alloc((size_t)256 * 256 * 2);
  float* bias_qkv = (float*)alloc(768 * 4);
  float* bias_f   = (float*)alloc(512 * 4);
  bf16* xm_nhwc   = (bf16*)alloc((size_t)Ttok * 256 * 2);
  bf16* xf_nhwc   = (bf16*)alloc((size_t)Ttok * 32 * 2);
  bf16* xc        = (bf16*)alloc((size_t)Ttok * 256 * 2);
  bf16* fc        = (bf16*)alloc((size_t)Ttok * 256 * 2);
  bf16* qkv       = (bf16*)alloc((size_t)Ttok * 768 * 2);
  bf16* attn_out  = xm_nhwc;          // reuse (dead after cmap conv)
  bf16* proj_out  = fc;               // reuse (dead after qkv GEMMs)
  bf16* convout   = qkv;              // reuse (dead after attention; bf16 NHWC)
  bf16* zpb = (bf16*)zp;

  k_zero4k<<<4, 256, 0, stream>>>(zp);
  k_permconv<<<(256 * 9 * 256 + 255) / 256, 256, 0, stream>>>(cmap_w, cmap_wT, 256);
  k_permconv<<<(256 * 9 * 256 + 255) / 256, 256, 0, stream>>>(cout_w, cout_wT, 256);
  k_permconv<<<(256 * 9 * 32 + 255) / 256, 256, 0, stream>>>(cfeat_w, cfeat_wT, 32);
  k_castf2b<<<256, 256, 0, stream>>>(qxmap_w, lin_qkv_wT, 65536);
  k_castf2b<<<256, 256, 0, stream>>>(kxmap_w, lin_qkv_wT + 65536, 65536);
  k_castf2b<<<256, 256, 0, stream>>>(vxmap_w, lin_qkv_wT + 131072, 65536);
  k_castf2b<<<256, 256, 0, stream>>>(qxfeat_w, lin_f_wT, 65536);
  k_castf2b<<<256, 256, 0, stream>>>(kxfeat_w, lin_f_wT + 65536, 65536);
  k_castf2b<<<256, 256, 0, stream>>>(proj_w, proj_wT, 65536);
  k_copyf<<<1, 256, 0, stream>>>(qxmap_b, bias_qkv, 256);
  k_copyf<<<1, 256, 0, stream>>>(kxmap_b, bias_qkv + 256, 256);
  k_copyf<<<1, 256, 0, stream>>>(vxmap_b, bias_qkv + 512, 256);
  k_copyf<<<1, 256, 0, stream>>>(qxfeat_b, bias_f, 256);
  k_copyf<<<1, 256, 0, stream>>>(kxfeat_b, bias_f + 256, 256);

  k_tohwc<<<dim3(Bimg * Himg, Wimg / 32, 256 / 32), 256, 0, stream>>>(xmap, xm_nhwc, 256);
  k_tohwc<<<dim3(Bimg * Himg, Wimg / 32, 1), 256, 0, stream>>>(xfeat, xf_nhwc, 32);

  dim3 blk(256);
  const int NT = Ttok / 128;   // 2048 row tiles
  // conv cmap -> xc
  k_gemm<256, 9, 0><<<dim3(NT * 2), blk, 0, stream>>>(
      xm_nhwc, cmap_wT, cmap_b, xc, 256, nullptr, zpb, 2);
  // conv cfeat -> fc
  k_gemm<32, 9, 0><<<dim3(NT * 2), blk, 0, stream>>>(
      xf_nhwc, cfeat_wT, cfeat_b, fc, 256, nullptr, zpb, 2);
  // v-linear -> qkv[:,512:768]
  k_gemm<256, 1, 0><<<dim3(NT * 2), blk, 0, stream>>>(
      xc, lin_qkv_wT + 131072, bias_qkv + 512, qkv + 512, 768, nullptr, zpb, 2);
  // gated q,k -> qkv[:,0:512]
  k_gemm_qkv<<<dim3(NT * 4), blk, 0, stream>>>(
      xc, fc, lin_qkv_wT, lin_f_wT, bias_qkv, bias_f, qkv);
  // MFMA window attention
  k_attn_mfma<<<dim3(4096 * 2), blk, 0, stream>>>(qkv, attn_out);
  // proj GEMM
  k_gemm<256, 1, 0><<<dim3(NT * 2), blk, 0, stream>>>(
      attn_out, proj_wT, proj_b, proj_out, 256, nullptr, zpb, 2);
  // conv cout + bias + identity -> convout (NHWC bf16)
  k_gemm<256, 9, 2><<<dim3(NT * 2), blk, 0, stream>>>(
      proj_out, cout_wT, cout_b, convout, 256, xc, zpb, 2);
  // NHWC bf16 -> NCHW fp32 final
  k_tochw<<<dim3(Bimg * Himg, Wimg / 32, 256 / 32), 256, 0, stream>>>(convout, (float*)d_out);
}

// Round 7
// 1556.297 us; speedup vs baseline: 1.1618x; 1.0621x over previous
//
#include <hip/hip_runtime.h>
#include <hip/hip_bf16.h>
#include <cstdint>
#include <math.h>

using bf16 = __hip_bfloat16;
typedef __attribute__((ext_vector_type(4))) float f32x4;
typedef __attribute__((ext_vector_type(8))) short s16x8;
typedef __attribute__((ext_vector_type(4))) short s16x4;

#define AS3(p) ((__attribute__((address_space(3))) void *)(p))
#define AS1(p) ((const __attribute__((address_space(1))) void *)(p))

static constexpr int Himg = 256, Wimg = 256, Bimg = 4;
static constexpr int HWimg = Himg * Wimg;
static constexpr int Ttok = Bimg * HWimg;   // 262144 tokens

__device__ __forceinline__ void gld16(bf16* lds, const bf16* g) {
  __builtin_amdgcn_global_load_lds(AS1(g), AS3(lds), 16, 0, 0);
}

__device__ __forceinline__ unsigned short f2u(float f) {
  bf16 b = __float2bfloat16(f);
  unsigned short u; __builtin_memcpy(&u, &b, 2); return u;
}

// XCD-chunked remap: hw round-robin (bid%8) -> contiguous logical chunks.
__device__ __forceinline__ void remap_tile(int bid, int total, int NY, int BMv, int& t0, int& n0) {
  int lin = (bid & 7) * (total >> 3) + (bid >> 3);
  t0 = (lin / NY) * BMv;
  n0 = (lin % NY) * 128;
}

// ---------------- prep kernels ----------------
__global__ void k_zero4k(float* p) {
  p[blockIdx.x * 256 + threadIdx.x] = 0.f;
}

__global__ void k_castf2b(const float* __restrict__ s, bf16* __restrict__ d, int n) {
  int i = blockIdx.x * 256 + threadIdx.x;
  if (i < n) d[i] = __float2bfloat16(s[i]);
}

__global__ void k_copyf(const float* __restrict__ s, float* __restrict__ d, int n) {
  int i = blockIdx.x * 256 + threadIdx.x;
  if (i < n) d[i] = s[i];
}

// conv weight permute: OIHW fp32 -> [O][tap][I] bf16
__global__ void k_permconv(const float* __restrict__ w, bf16* __restrict__ o, int I) {
  int idx = blockIdx.x * 256 + threadIdx.x;
  int tot = 256 * 9 * I;
  if (idx >= tot) return;
  int i   = idx % I;
  int rem = idx / I;
  int tap = rem % 9;
  int oc  = rem / 9;
  o[idx] = __float2bfloat16(w[(oc * I + i) * 9 + tap]);
}

// NCHW fp32 -> NHWC bf16
__global__ void k_tohwc(const float* __restrict__ src, bf16* __restrict__ dst, int C) {
  int bh = blockIdx.x;
  int w0 = blockIdx.y * 32;
  int c0 = blockIdx.z * 32;
  int b = bh / Himg, h = bh % Himg;
  __shared__ float tile[32][33];
  int tid = threadIdx.x;
  int x = tid & 31, y = tid >> 5;
  const float* sp = src + (size_t)b * C * HWimg + (size_t)h * Wimg;
#pragma unroll
  for (int p = 0; p < 4; ++p) {
    int cl = y + p * 8;
    tile[cl][x] = sp[(size_t)(c0 + cl) * HWimg + w0 + x];
  }
  __syncthreads();
#pragma unroll
  for (int p = 0; p < 4; ++p) {
    int wl = y + p * 8;
    dst[((size_t)bh * Wimg + w0 + wl) * C + c0 + x] = __float2bfloat16(tile[x][wl]);
  }
}

// NHWC bf16 -> NCHW fp32 (final output)
__global__ void k_tochw(const bf16* __restrict__ src, float* __restrict__ dst) {
  int bh = blockIdx.x, w0 = blockIdx.y * 32, c0 = blockIdx.z * 32;
  int b = bh >> 8, h = bh & 255;
  __shared__ float tile[32][33];
  int tid = threadIdx.x, x = tid & 31, y = tid >> 5;
  const bf16* sp = src + (size_t)bh * Wimg * 256;
#pragma unroll
  for (int p = 0; p < 4; ++p) {
    int wl = y + p * 8;
    tile[wl][x] = __bfloat162float(sp[(size_t)(w0 + wl) * 256 + c0 + x]);
  }
  __syncthreads();
#pragma unroll
  for (int p = 0; p < 4; ++p) {
    int cl = y + p * 8;
    dst[(((size_t)b * 256 + c0 + cl) * Himg + h) * Wimg + w0 + x] = tile[x][cl];
  }
}

// ---------------- implicit-GEMM / conv kernel ----------------
// BM=256 x BN=128, 4 waves, per-wave 128x64 (acc[8][4]) -> 384 B LDS / MFMA.
// Triple-buffered static LDS, counted vmcnt(6), XOR bank swizzle both sides.
// EPI 0: outb[t*ldo+col] = bf16(acc+bias)
// EPI 2: outb[t*256+col] = bf16(acc + bias + float(ident[t*256+col]))
template <int CIN, int TAPS, int EPI>
__global__ void __launch_bounds__(256, 2)
k_gemm(const bf16* __restrict__ Ain, const bf16* __restrict__ BT,
       const float* __restrict__ bias,
       bf16* __restrict__ outb, int ldo,
       const bf16* __restrict__ ident,
       const bf16* __restrict__ zp, int NY)
{
  constexpr int KTOT = TAPS * CIN;
  constexpr int NK = KTOT / 32;
  int t0, n0;
  remap_tile(blockIdx.x, gridDim.x, NY, 256, t0, n0);
  const int tid = threadIdx.x;
  const int wave = tid >> 6, lane = tid & 63;
  const int seg = lane & 3;
  const int rr  = lane >> 2;

  __shared__ bf16 sA0[256 * 32];
  __shared__ bf16 sA1[256 * 32];
  __shared__ bf16 sA2[256 * 32];
  __shared__ bf16 sB0[128 * 32];
  __shared__ bf16 sB1[128 * 32];
  __shared__ bf16 sB2[128 * 32];

  f32x4 acc[8][4] = {};

  const int wr = wave >> 1, wc = wave & 1;
  const int fr = lane & 15, fq = lane >> 4;
  const int sseg = (seg ^ ((rr >> 1) & 3)) * 8;       // staging source swizzle
  const int slot = (fq ^ ((fr >> 1) & 3)) * 8;        // read-side swizzle

#define STAGE(WA, WB, KSV) do {                                                 \
    const int k0_ = (KSV) * 32;                                                 \
    const int tap_ = k0_ / CIN;                                                 \
    const int c0_ = k0_ - tap_ * CIN;                                           \
    const int dy_ = tap_ / 3 - 1, dx_ = tap_ % 3 - 1;                           \
    _Pragma("unroll") for (int i_ = 0; i_ < 4; ++i_) {                          \
      const int g_ = i_ * 4 + wave;                                             \
      const int t_ = t0 + g_ * 16 + rr;                                         \
      const bf16* src_;                                                         \
      if (TAPS == 1) {                                                          \
        src_ = Ain + (size_t)t_ * CIN + k0_ + sseg;                             \
      } else {                                                                  \
        const int hh_ = ((t_ >> 8) & 255) + dy_, ww_ = (t_ & 255) + dx_;        \
        const bool v_ = ((unsigned)hh_ < 256u) && ((unsigned)ww_ < 256u);       \
        const long gi_ = (long)t_ + dy_ * Wimg + dx_;                           \
        src_ = v_ ? (Ain + gi_ * CIN + c0_ + sseg) : (zp + sseg);               \
      }                                                                         \
      gld16(WA + g_ * 16 * 32, src_);                                           \
    }                                                                           \
    _Pragma("unroll") for (int i_ = 0; i_ < 2; ++i_) {                          \
      const int g_ = i_ * 4 + wave;                                             \
      gld16(WB + g_ * 16 * 32,                                                  \
            BT + (size_t)(n0 + g_ * 16 + rr) * KTOT + k0_ + sseg);              \
    }                                                                           \
  } while (0)

#define GSTEP(RA, RB, WA, WB, KSV, LASTF) do {                                  \
    if (LASTF) { asm volatile("s_waitcnt vmcnt(0)" ::: "memory"); }             \
    else       { asm volatile("s_waitcnt vmcnt(6)" ::: "memory"); }             \
    __builtin_amdgcn_s_barrier();                                               \
    s16x8 af_[8], bf_[4];                                                       \
    _Pragma("unroll") for (int m_ = 0; m_ < 8; ++m_)                            \
      af_[m_] = *(const s16x8*)(RA + (wr * 128 + m_ * 16 + fr) * 32 + slot);    \
    _Pragma("unroll") for (int n_ = 0; n_ < 4; ++n_)                            \
      bf_[n_] = *(const s16x8*)(RB + (wc * 64 + n_ * 16 + fr) * 32 + slot);     \
    if ((KSV) + 2 < NK) STAGE(WA, WB, (KSV) + 2);                               \
    __builtin_amdgcn_s_setprio(1);                                              \
    _Pragma("unroll") for (int m_ = 0; m_ < 8; ++m_)                            \
      _Pragma("unroll") for (int n_ = 0; n_ < 4; ++n_)                          \
        acc[m_][n_] = __builtin_amdgcn_mfma_f32_16x16x32_bf16(af_[m_], bf_[n_], acc[m_][n_], 0, 0, 0); \
    __builtin_amdgcn_s_setprio(0);                                              \
  } while (0)

  STAGE(sA0, sB0, 0);
  STAGE(sA1, sB1, 1);

  constexpr int NMAIN = ((NK - 1) / 3) * 3;   // main-loop steps, multiple of 3, < NK
  int ks = 0;
#pragma unroll 1
  for (; ks < NMAIN; ks += 3) {
    GSTEP(sA0, sB0, sA2, sB2, ks,     false);
    GSTEP(sA1, sB1, sA0, sB0, ks + 1, false);
    GSTEP(sA2, sB2, sA1, sB1, ks + 2, false);
  }
  constexpr int TREM = NK - NMAIN;            // 1..3 tail steps
  if constexpr (TREM == 3) {
    GSTEP(sA0, sB0, sA2, sB2, NMAIN,     false);
    GSTEP(sA1, sB1, sA0, sB0, NMAIN + 1, false);
    GSTEP(sA2, sB2, sA1, sB1, NMAIN + 2, true);
  } else if constexpr (TREM == 2) {
    GSTEP(sA0, sB0, sA2, sB2, NMAIN,     false);
    GSTEP(sA1, sB1, sA0, sB0, NMAIN + 1, true);
  } else {
    GSTEP(sA0, sB0, sA2, sB2, NMAIN,     true);
  }
#undef GSTEP
#undef STAGE

#pragma unroll
  for (int m = 0; m < 8; ++m) {
#pragma unroll
    for (int n = 0; n < 4; ++n) {
      const int col = n0 + wc * 64 + n * 16 + fr;
#pragma unroll
      for (int j = 0; j < 4; ++j) {
        const int row = wr * 128 + m * 16 + fq * 4 + j;
        const size_t t = (size_t)t0 + row;
        float v = acc[m][n][j] + bias[col];
        if (EPI == 0) {
          outb[t * ldo + col] = __float2bfloat16(v);
        } else {
          v += __bfloat162float(ident[t * 256 + col]);
          outb[t * 256 + col] = __float2bfloat16(v);
        }
      }
    }
  }
}

// ---------------- gated dual GEMM (static triple-buffer pipeline + swizzle) ----------------
// out[t*768+col] = (A_m B_m + b_m) * sigmoid(A_f B_f + b_f); 16 flat steps (m/f alternating).
__global__ void __launch_bounds__(256, 2)
k_gemm_qkv(const bf16* __restrict__ Am, const bf16* __restrict__ Af,
           const bf16* __restrict__ Bm, const bf16* __restrict__ Bf,
           const float* __restrict__ bm, const float* __restrict__ bfi,
           bf16* __restrict__ out)
{
  int t0, n0;
  remap_tile(blockIdx.x, gridDim.x, 4, 128, t0, n0);
  const int tid = threadIdx.x;
  const int wave = tid >> 6, lane = tid & 63;
  const int seg = lane & 3;
  const int rr  = lane >> 2;

  __shared__ bf16 sA0[128 * 32];
  __shared__ bf16 sA1[128 * 32];
  __shared__ bf16 sA2[128 * 32];
  __shared__ bf16 sB0[128 * 32];
  __shared__ bf16 sB1[128 * 32];
  __shared__ bf16 sB2[128 * 32];

  f32x4 accm[4][4] = {};
  f32x4 accf[4][4] = {};

  const int wr = wave >> 1, wc = wave & 1;
  const int fr = lane & 15, fq = lane >> 4;
  const int sseg = (seg ^ ((rr >> 1) & 3)) * 8;
  const int slot = (fq ^ ((fr >> 1) & 3)) * 8;

#define STAGEQ(WA, WB, SV) do {                                                 \
    const int k0_ = ((SV) >> 1) * 32;                                           \
    const bf16* A_ = ((SV) & 1) ? Af : Am;                                      \
    const bf16* B_ = ((SV) & 1) ? Bf : Bm;                                      \
    _Pragma("unroll") for (int i_ = 0; i_ < 2; ++i_) {                          \
      const int r_ = wave * 32 + i_ * 16 + rr;                                  \
      gld16(WA + (wave * 32 + i_ * 16) * 32, A_ + (size_t)(t0 + r_) * 256 + k0_ + sseg); \
      gld16(WB + (wave * 32 + i_ * 16) * 32, B_ + (size_t)(n0 + r_) * 256 + k0_ + sseg); \
    }                                                                           \
  } while (0)

#define QSTEP(RA, RB, WA, WB, SV, LASTF) do {                                   \
    if (LASTF) { asm volatile("s_waitcnt vmcnt(0)" ::: "memory"); }             \
    else       { asm volatile("s_waitcnt vmcnt(4)" ::: "memory"); }             \
    __builtin_amdgcn_s_barrier();                                               \
    s16x8 af_[4], bf_[4];                                                       \
    _Pragma("unroll") for (int m_ = 0; m_ < 4; ++m_)                            \
      af_[m_] = *(const s16x8*)(RA + (wr * 64 + m_ * 16 + fr) * 32 + slot);     \
    _Pragma("unroll") for (int n_ = 0; n_ < 4; ++n_)                            \
      bf_[n_] = *(const s16x8*)(RB + (wc * 64 + n_ * 16 + fr) * 32 + slot);     \
    if ((SV) + 2 < 16) STAGEQ(WA, WB, (SV) + 2);                                \
    __builtin_amdgcn_s_setprio(1);                                              \
    if ((SV) & 1) {                                                             \
      _Pragma("unroll") for (int m_ = 0; m_ < 4; ++m_)                          \
        _Pragma("unroll") for (int n_ = 0; n_ < 4; ++n_)                        \
          accf[m_][n_] = __builtin_amdgcn_mfma_f32_16x16x32_bf16(af_[m_], bf_[n_], accf[m_][n_], 0, 0, 0); \
    } else {                                                                    \
      _Pragma("unroll") for (int m_ = 0; m_ < 4; ++m_)                          \
        _Pragma("unroll") for (int n_ = 0; n_ < 4; ++n_)                        \
          accm[m_][n_] = __builtin_amdgcn_mfma_f32_16x16x32_bf16(af_[m_], bf_[n_], accm[m_][n_], 0, 0, 0); \
    }                                                                           \
    __builtin_amdgcn_s_setprio(0);                                              \
  } while (0)

  STAGEQ(sA0, sB0, 0);
  STAGEQ(sA1, sB1, 1);

  int s = 0;
#pragma unroll 1
  for (; s < 15; s += 3) {
    QSTEP(sA0, sB0, sA2, sB2, s,     false);
    QSTEP(sA1, sB1, sA0, sB0, s + 1, false);
    QSTEP(sA2, sB2, sA1, sB1, s + 2, false);
  }
  QSTEP(sA0, sB0, sA2, sB2, 15, true);
#undef QSTEP
#undef STAGEQ

#pragma unroll
  for (int m = 0; m < 4; ++m) {
#pragma unroll
    for (int n = 0; n < 4; ++n) {
      const int col = n0 + wc * 64 + n * 16 + fr;
#pragma unroll
      for (int j = 0; j < 4; ++j) {
        const int row = wr * 64 + m * 16 + fq * 4 + j;
        const size_t t = (size_t)t0 + row;
        float v = accm[m][n][j] + bm[col];
        const float g = accf[m][n][j] + bfi[col];
        v *= 1.f / (1.f + __expf(-g));
        out[t * 768 + col] = __float2bfloat16(v);
      }
    }
  }
}

// ---------------- MFMA window attention (coalesced LDS staging) ----------------
__global__ void __launch_bounds__(256, 2)
k_attn_mfma(const bf16* __restrict__ qkv, bf16* __restrict__ out) {
  __shared__ short smem[4 * 7424];   // 14848 B per wave
  const int tid = threadIdx.x;
  const int wave = tid >> 6, lane = tid & 63;
  const int fr = lane & 15, fq = lane >> 4;
  const int wi = blockIdx.x >> 1;
  const int head = (blockIdx.x & 1) * 4 + wave;
  const int b = wi >> 10, rem = wi & 1023, wh = rem >> 5, ww = rem & 31;
  const size_t tbase = (size_t)b * HWimg + (size_t)(wh * 8) * Wimg + ww * 8;

  short* Qs = smem + wave * 7424;     // [64][40]
  short* Ks = Qs + 2560;              // [64][40]
  short* VT = Qs + 5120;              // [32][72]
  short* P  = Qs;                     // [64][72] alias
  short* Ol = Qs;                     // [64][40] alias

  auto tok = [&](int i) -> size_t {
    return tbase + (size_t)(i >> 3) * Wimg + (i & 7);
  };

  {
    const bf16* tb = qkv + tok(lane) * 768 + head * 32;
#pragma unroll
    for (int c = 0; c < 4; ++c) {
      s16x8 qv = *(const s16x8*)(tb + c * 8);
      s16x8 kv = *(const s16x8*)(tb + 256 + c * 8);
      s16x8 vv = *(const s16x8*)(tb + 512 + c * 8);
      *(s16x8*)(Qs + lane * 40 + c * 8) = qv;
      *(s16x8*)(Ks + lane * 40 + c * 8) = kv;
#pragma unroll
      for (int e = 0; e < 8; ++e) VT[(c * 8 + e) * 72 + lane] = vv[e];
    }
  }

  s16x8 kf[4], qf[4];
#pragma unroll
  for (int m = 0; m < 4; ++m)
    kf[m] = *(const s16x8*)(Ks + (fr + 16 * m) * 40 + fq * 8);
#pragma unroll
  for (int n = 0; n < 4; ++n)
    qf[n] = *(const s16x8*)(Qs + (fr + 16 * n) * 40 + fq * 8);

  f32x4 st[4][4] = {};
#pragma unroll
  for (int m = 0; m < 4; ++m)
#pragma unroll
    for (int n = 0; n < 4; ++n)
      st[m][n] = __builtin_amdgcn_mfma_f32_16x16x32_bf16(kf[m], qf[n], st[m][n], 0, 0, 0);

  const float scale = 0.17677669529663688f;  // 1/sqrt(32)
  float invs[4];
#pragma unroll
  for (int n = 0; n < 4; ++n) {
    float mx = -1e30f;
#pragma unroll
    for (int m = 0; m < 4; ++m)
#pragma unroll
      for (int j = 0; j < 4; ++j) mx = fmaxf(mx, st[m][n][j]);
    mx = fmaxf(mx, __shfl_xor(mx, 16));
    mx = fmaxf(mx, __shfl_xor(mx, 32));
    float sum = 0.f;
#pragma unroll
    for (int m = 0; m < 4; ++m) {
      s16x4 pk;
#pragma unroll
      for (int j = 0; j < 4; ++j) {
        float e = __expf((st[m][n][j] - mx) * scale);
        sum += e;
        pk[j] = (short)f2u(e);
      }
      *(s16x4*)(P + (fr + 16 * n) * 72 + 16 * m + 4 * fq) = pk;
    }
    sum += __shfl_xor(sum, 16);
    sum += __shfl_xor(sum, 32);
    invs[n] = 1.f / sum;
  }

  f32x4 oc[4][2] = {};
#pragma unroll
  for (int ks = 0; ks < 2; ++ks) {
    s16x8 pf[4], vf[2];
#pragma unroll
    for (int m = 0; m < 4; ++m)
      pf[m] = *(const s16x8*)(P + (fr + 16 * m) * 72 + ks * 32 + fq * 8);
#pragma unroll
    for (int n = 0; n < 2; ++n)
      vf[n] = *(const s16x8*)(VT + (fr + 16 * n) * 72 + ks * 32 + fq * 8);
#pragma unroll
    for (int m = 0; m < 4; ++m)
#pragma unroll
      for (int n = 0; n < 2; ++n)
        oc[m][n] = __builtin_amdgcn_mfma_f32_16x16x32_bf16(pf[m], vf[n], oc[m][n], 0, 0, 0);
  }

#pragma unroll
  for (int m = 0; m < 4; ++m)
#pragma unroll
    for (int j = 0; j < 4; ++j) {
      const float inv = __shfl(invs[m], 4 * fq + j);
      const int q = 16 * m + 4 * fq + j;
#pragma unroll
      for (int n = 0; n < 2; ++n)
        Ol[q * 40 + fr + 16 * n] = (short)f2u(oc[m][n][j] * inv);
    }
  {
    bf16* op = out + tok(lane) * 256 + head * 32;
#pragma unroll
    for (int c = 0; c < 4; ++c)
      *(s16x8*)(op + c * 8) = *(const s16x8*)(Ol + lane * 40 + c * 8);
  }
}

// ---------------- host ----------------
extern "C" void kernel_launch(void* const* d_in, const int* in_sizes, int n_in,
                              void* d_out, int out_size, void* d_ws, size_t ws_size,
                              hipStream_t stream) {
  const float* xmap    = (const float*)d_in[0];
  const float* xfeat   = (const float*)d_in[1];
  const float* cmap_w  = (const float*)d_in[2];
  const float* cmap_b  = (const float*)d_in[3];
  const float* cfeat_w = (const float*)d_in[4];
  const float* cfeat_b = (const float*)d_in[5];
  const float* qxmap_w = (const float*)d_in[6];
  const float* qxmap_b = (const float*)d_in[7];
  const float* kxmap_w = (const float*)d_in[8];
  const float* kxmap_b = (const float*)d_in[9];
  const float* vxmap_w = (const float*)d_in[10];
  const float* vxmap_b = (const float*)d_in[11];
  const float* qxfeat_w = (const float*)d_in[12];
  const float* qxfeat_b = (const float*)d_in[13];
  const float* kxfeat_w = (const float*)d_in[14];
  const float* kxfeat_b = (const float*)d_in[15];
  const float* proj_w  = (const float*)d_in[16];
  const float* proj_b  = (const float*)d_in[17];
  const float* cout_w  = (const float*)d_in[18];
  const float* cout_b  = (const float*)d_in[19];

  uint8_t* ws = (uint8_t*)d_ws;
  size_t off = 0;
  auto alloc = [&](size_t bytes) -> void* {
    void* p = ws + off;
    off += (bytes + 255) & ~(size_t)255;
    return p;
  };
  float* zp       = (float*)alloc(4096);
  bf16* cmap_wT   = (bf16*)alloc((size_t)2304 * 256 * 2);
  bf16* cout_wT   = (bf16*)alloc((size_t)2304 * 256 * 2);
  bf16* cfeat_wT  = (bf16*)alloc((size_t)288 * 256 * 2);
  bf16* lin_qkv_wT= (bf16*)alloc((size_t)768 * 256 * 2);
  bf16* lin_f_wT  = (bf16*)alloc((size_t)512 * 256 * 2);
  bf16* proj_wT   = (bf16*)alloc((size_t)256 * 256 * 2);
  float* bias_qkv = (float*)alloc(768 * 4);
  float* bias_f   = (float*)alloc(512 * 4);
  bf16* xm_nhwc   = (bf16*)alloc((size_t)Ttok * 256 * 2);
  bf16* xf_nhwc   = (bf16*)alloc((size_t)Ttok * 32 * 2);
  bf16* xc        = (bf16*)alloc((size_t)Ttok * 256 * 2);
  bf16* fc        = (bf16*)alloc((size_t)Ttok * 256 * 2);
  bf16* qkv       = (bf16*)alloc((size_t)Ttok * 768 * 2);
  bf16* attn_out  = xm_nhwc;          // reuse (dead after cmap conv)
  bf16* proj_out  = fc;               // reuse (dead after qkv GEMMs)
  bf16* convout   = qkv;              // reuse (dead after attention; bf16 NHWC)
  bf16* zpb = (bf16*)zp;

  k_zero4k<<<4, 256, 0, stream>>>(zp);
  k_permconv<<<(256 * 9 * 256 + 255) / 256, 256, 0, stream>>>(cmap_w, cmap_wT, 256);
  k_permconv<<<(256 * 9 * 256 + 255) / 256, 256, 0, stream>>>(cout_w, cout_wT, 256);
  k_permconv<<<(256 * 9 * 32 + 255) / 256, 256, 0, stream>>>(cfeat_w, cfeat_wT, 32);
  k_castf2b<<<256, 256, 0, stream>>>(qxmap_w, lin_qkv_wT, 65536);
  k_castf2b<<<256, 256, 0, stream>>>(kxmap_w, lin_qkv_wT + 65536, 65536);
  k_castf2b<<<256, 256, 0, stream>>>(vxmap_w, lin_qkv_wT + 131072, 65536);
  k_castf2b<<<256, 256, 0, stream>>>(qxfeat_w, lin_f_wT, 65536);
  k_castf2b<<<256, 256, 0, stream>>>(kxfeat_w, lin_f_wT + 65536, 65536);
  k_castf2b<<<256, 256, 0, stream>>>(proj_w, proj_wT, 65536);
  k_copyf<<<1, 256, 0, stream>>>(qxmap_b, bias_qkv, 256);
  k_copyf<<<1, 256, 0, stream>>>(kxmap_b, bias_qkv + 256, 256);
  k_copyf<<<1, 256, 0, stream>>>(vxmap_b, bias_qkv + 512, 256);
  k_copyf<<<1, 256, 0, stream>>>(qxfeat_b, bias_f, 256);
  k_copyf<<<1, 256, 0, stream>>>(kxfeat_b, bias_f + 256, 256);

  k_tohwc<<<dim3(Bimg * Himg, Wimg / 32, 256 / 32), 256, 0, stream>>>(xmap, xm_nhwc, 256);
  k_tohwc<<<dim3(Bimg * Himg, Wimg / 32, 1), 256, 0, stream>>>(xfeat, xf_nhwc, 32);

  dim3 blk(256);
  const int NT256 = Ttok / 256;   // 1024 row tiles of 256
  // conv cmap -> xc
  k_gemm<256, 9, 0><<<dim3(NT256 * 2), blk, 0, stream>>>(
      xm_nhwc, cmap_wT, cmap_b, xc, 256, nullptr, zpb, 2);
  // conv cfeat -> fc
  k_gemm<32, 9, 0><<<dim3(NT256 * 2), blk, 0, stream>>>(
      xf_nhwc, cfeat_wT, cfeat_b, fc, 256, nullptr, zpb, 2);
  // v-linear -> qkv[:,512:768]
  k_gemm<256, 1, 0><<<dim3(NT256 * 2), blk, 0, stream>>>(
      xc, lin_qkv_wT + 131072, bias_qkv + 512, qkv + 512, 768, nullptr, zpb, 2);
  // gated q,k -> qkv[:,0:512]
  k_gemm_qkv<<<dim3((Ttok / 128) * 4), blk, 0, stream>>>(
      xc, fc, lin_qkv_wT, lin_f_wT, bias_qkv, bias_f, qkv);
  // MFMA window attention
  k_attn_mfma<<<dim3(4096 * 2), blk, 0, stream>>>(qkv, attn_out);
  // proj GEMM
  k_gemm<256, 1, 0><<<dim3(NT256 * 2), blk, 0, stream>>>(
      attn_out, proj_wT, proj_b, proj_out, 256, nullptr, zpb, 2);
  // conv cout + bias + identity -> convout (NHWC bf16)
  k_gemm<256, 9, 2><<<dim3(NT256 * 2), blk, 0, stream>>>(
      proj_out, cout_wT, cout_b, convout, 256, xc, zpb, 2);
  // NHWC bf16 -> NCHW fp32 final
  k_tochw<<<dim3(Bimg * Himg, Wimg / 32, 256 / 32), 256, 0, stream>>>(convout, (float*)d_out);
}